// Round 4
// baseline (213.519 us; speedup 1.0000x reference)
//
#include <hip/hip_runtime.h>
#include <hip/hip_bf16.h>

typedef float f32x4 __attribute__((ext_vector_type(4)));
typedef short s16x8 __attribute__((ext_vector_type(8)));
typedef unsigned int u32;
typedef u32 u32x2 __attribute__((ext_vector_type(2)));

#define DIST_SCALE 25.0f

__device__ __forceinline__ unsigned short f2b(float f) {
  union { float f; unsigned u; } v; v.f = f;
  unsigned r = v.u + 0x7fffu + ((v.u >> 16) & 1u);
  return (unsigned short)(r >> 16);
}

__device__ __forceinline__ u32 cvtpk(float lo, float hi) {
  u32 r;
  asm("v_cvt_pk_bf16_f32 %0, %1, %2" : "=v"(r) : "v"(lo), "v"(hi));
  return r;
}

// H: [128 samples][128 ch] bf16, 256B rows, XOR-swizzled (balanced for b64 writes / b128 reads)
__device__ __forceinline__ int swzH(int s, int chbyte) {
  return (s * 256 + chbyte) ^ ((s & 7) << 4);
}

__global__ void prep_weights(const float* __restrict__ W1, const float* __restrict__ W2,
                             const float* __restrict__ W3, unsigned short* __restrict__ ws) {
  int t = blockIdx.x * 256 + threadIdx.x;
  int stride = gridDim.x * 256;
  // W1aT[n][k] (k padded 27->32 with ZEROS - annihilates X pad garbage)
  for (int i = t; i < 128 * 32; i += stride) {
    int n = i >> 5, k = i & 31;
    ws[i] = (k < 27) ? f2b(W1[k * 128 + n]) : (unsigned short)0;
  }
  unsigned short* w2t = ws + 4096;
  for (int i = t; i < 128 * 128; i += stride) {
    int n = i >> 7, k = i & 127;
    w2t[i] = f2b(W2[k * 128 + n]);
  }
  unsigned short* w3t = ws + 4096 + 16384;   // W3T[n(16 pad)][k(128)]
  for (int i = t; i < 16 * 128; i += stride) {
    int n = i >> 7, k = i & 127;
    w3t[i] = (n < 3) ? f2b(W3[k * 3 + n]) : (unsigned short)0;
  }
}

__global__ __launch_bounds__(256, 3) void nerf_main(
    const float* __restrict__ dens, const float* __restrict__ app,
    const float* __restrict__ vdirs, const float* __restrict__ dists,
    const float* __restrict__ W1, const float* __restrict__ b1,
    const float* __restrict__ b2v, const float* __restrict__ b3v,
    const unsigned short* __restrict__ wsb, float* __restrict__ out) {
  __shared__ float Xf[128 * 27 + 8];          // block-shared f32 staging (+8 zero pad)
  __shared__ unsigned short H[128 * 128];     // block-shared activations [s][ch]
  __shared__ float wbuf[256];
  __shared__ float hcbuf[128];
  __shared__ float b2s[128];
  __shared__ float featbuf[40];
  __shared__ float red[4][4];

  const int t = threadIdx.x;
  const int lane = t & 63;
  const int wv = t >> 6;
  const int r = blockIdx.x;

  const unsigned short* W1aT = wsb;
  const unsigned short* W2T = wsb + 4096;
  const unsigned short* W3T = wsb + 4096 + 16384;
  char* Hb = (char*)H;

  const int cl = lane & 15;    // A-row / C-col index
  const int kg = lane >> 4;    // k-group; C rows = kg*4+i
  const int chBase = wv * 32;  // this wave's output-channel slice

  // ---------------- prologue ----------------
  if (t < 39) {   // view-dir features: [vd(3), sin(18), cos(18)]
    float val;
    if (t < 3) val = vdirs[r * 3 + t];
    else {
      int jj = t - 3;
      int trig = jj / 18;
      int rem = jj % 18;
      int c = rem / 6, k = rem % 6;
      float v = vdirs[r * 3 + c] * (float)(1 << k);
      val = trig ? cosf(v) : sinf(v);
    }
    featbuf[t] = val;
  }
  if (t >= 64 && t < 192) b2s[t - 64] = b2v[t - 64];
  if (t < 8) Xf[3456 + t] = 0.0f;   // zero pad: finite for s=127 k>=27 reads
  // transmittance/weight scan (wave 0, 4 samples/lane)
  if (wv == 0) {
    const float4 dv = *(const float4*)(dens + (size_t)r * 256 + lane * 4);
    const float4 tv = *(const float4*)(dists + (size_t)r * 256 + lane * 4);
    float f[4], al[4];
    float dl[4] = {dv.x, dv.y, dv.z, dv.w};
    float tl[4] = {tv.x, tv.y, tv.z, tv.w};
    float p = 1.0f;
#pragma unroll
    for (int q = 0; q < 4; ++q) {
      float sg = fmaxf(dl[q], 0.0f);
      float e = __expf(-sg * tl[q] * DIST_SCALE);
      al[q] = 1.0f - e;
      f[q] = e + 1e-10f;
      p *= f[q];
    }
    float P = p;
#pragma unroll
    for (int dlt = 1; dlt < 64; dlt <<= 1) {
      float v = __shfl_up(P, dlt, 64);
      if (lane >= dlt) P *= v;
    }
    float E = __shfl_up(P, 1, 64);
    if (lane == 0) E = 1.0f;
    float tr = E;
#pragma unroll
    for (int q = 0; q < 4; ++q) { wbuf[lane * 4 + q] = al[q] * tr; tr *= f[q]; }
  }
  __syncthreads();
  // per-ray folded layer-1 bias: h1c = b1 + vd_feats @ W1[27:66]
  if (t < 128) {
    float s = b1[t];
    for (int j = 0; j < 39; ++j) s += featbuf[j] * W1[(27 + j) * 128 + t];
    hcbuf[t] = s;
  }

  // ---- hoist this wave's weight slice into registers (one-time) ----
  s16x8 w1f[2], w2f[2][4], w3f[4];
#pragma unroll
  for (int nt = 0; nt < 2; ++nt)
    w1f[nt] = *(const s16x8*)(W1aT + (chBase + nt * 16 + cl) * 32 + kg * 8);
#pragma unroll
  for (int nt = 0; nt < 2; ++nt)
#pragma unroll
    for (int kk = 0; kk < 4; ++kk)
      w2f[nt][kk] = *(const s16x8*)(W2T + (chBase + nt * 16 + cl) * 128 + kk * 32 + kg * 8);
#pragma unroll
  for (int kk = 0; kk < 4; ++kk)
    w3f[kk] = *(const s16x8*)(W3T + cl * 128 + kk * 32 + kg * 8);

  __syncthreads();

  float pr = 0.0f, pg = 0.0f, pb = 0.0f, pw = 0.0f;
  const float b30 = b3v[0], b31 = b3v[1], b32 = b3v[2];

  for (int chunk = 0; chunk < 2; ++chunk) {
    const int sBase = chunk * 128;
    // ---- stage: each wave writes its own 32 samples (f32, contiguous, 16B aligned) ----
    {
      const float* slab = app + ((size_t)r * 256 + sBase + wv * 32) * 27;  // 864 f32
      float* Xw = Xf + wv * 864;
      f32x4 w0 = *(const f32x4*)(slab + 4 * lane);
      f32x4 w1 = *(const f32x4*)(slab + 4 * (lane + 64));
      f32x4 w2 = *(const f32x4*)(slab + 4 * (lane + 128));
      *(f32x4*)(Xw + 4 * lane) = w0;
      *(f32x4*)(Xw + 4 * (lane + 64)) = w1;
      *(f32x4*)(Xw + 4 * (lane + 128)) = w2;
      if (lane < 24) {
        f32x4 w3 = *(const f32x4*)(slab + 4 * (lane + 192));
        *(f32x4*)(Xw + 4 * (lane + 192)) = w3;
      }
    }
    __syncthreads();   // B1: X staged

    // ---- layer 1: C1[32ch][128s] = W1slice @ X^T ----
    f32x4 acc1[2][8] = {};
#pragma unroll
    for (int sh = 0; sh < 2; ++sh) {
      s16x8 bf[4];
#pragma unroll
      for (int q = 0; q < 4; ++q) {
        const int st = sh * 4 + q;
        const float* xr = Xf + 27 * (st * 16 + cl) + 8 * kg;  // k>=27 garbage killed by zero W cols
        union { u32 u[4]; s16x8 v; } ub;
#pragma unroll
        for (int p2 = 0; p2 < 4; ++p2) ub.u[p2] = cvtpk(xr[2 * p2], xr[2 * p2 + 1]);
        bf[q] = ub.v;
      }
#pragma unroll
      for (int q = 0; q < 4; ++q)
#pragma unroll
        for (int nt = 0; nt < 2; ++nt)
          acc1[nt][sh * 4 + q] =
              __builtin_amdgcn_mfma_f32_16x16x32_bf16(w1f[nt], bf[q], acc1[nt][sh * 4 + q], 0, 0, 0);
    }
    // epi: bias+relu -> H[s][ch]
#pragma unroll
    for (int nt = 0; nt < 2; ++nt) {
      f32x4 hc = *(const f32x4*)(hcbuf + chBase + nt * 16 + kg * 4);
#pragma unroll
      for (int st = 0; st < 8; ++st) {
        int s = st * 16 + cl;
        float v0 = fmaxf(acc1[nt][st][0] + hc[0], 0.0f);
        float v1 = fmaxf(acc1[nt][st][1] + hc[1], 0.0f);
        float v2 = fmaxf(acc1[nt][st][2] + hc[2], 0.0f);
        float v3 = fmaxf(acc1[nt][st][3] + hc[3], 0.0f);
        u32x2 pk = {cvtpk(v0, v1), cvtpk(v2, v3)};
        *(u32x2*)(Hb + swzH(s, (chBase + nt * 16 + kg * 4) * 2)) = pk;
      }
    }
    __syncthreads();   // B2: H1 complete

    // ---- layer 2: C2[32ch][128s] = W2slice @ H1^T (acc in regs, no H writes yet) ----
    f32x4 acc2[2][8] = {};
#pragma unroll
    for (int st = 0; st < 8; ++st) {
      s16x8 hbf[4];
#pragma unroll
      for (int kk = 0; kk < 4; ++kk)
        hbf[kk] = *(const s16x8*)(Hb + swzH(st * 16 + cl, (kk * 32 + kg * 8) * 2));
#pragma unroll
      for (int kk = 0; kk < 4; ++kk)
#pragma unroll
        for (int nt = 0; nt < 2; ++nt)
          acc2[nt][st] =
              __builtin_amdgcn_mfma_f32_16x16x32_bf16(w2f[nt][kk], hbf[kk], acc2[nt][st], 0, 0, 0);
    }
    __syncthreads();   // B3: all H1 reads done, safe to overwrite

    // epi: bias+relu -> H[s][ch] (in place)
#pragma unroll
    for (int nt = 0; nt < 2; ++nt) {
      f32x4 bb = *(const f32x4*)(b2s + chBase + nt * 16 + kg * 4);
#pragma unroll
      for (int st = 0; st < 8; ++st) {
        int s = st * 16 + cl;
        float v0 = fmaxf(acc2[nt][st][0] + bb[0], 0.0f);
        float v1 = fmaxf(acc2[nt][st][1] + bb[1], 0.0f);
        float v2 = fmaxf(acc2[nt][st][2] + bb[2], 0.0f);
        float v3 = fmaxf(acc2[nt][st][3] + bb[3], 0.0f);
        u32x2 pk = {cvtpk(v0, v1), cvtpk(v2, v3)};
        *(u32x2*)(Hb + swzH(s, (chBase + nt * 16 + kg * 4) * 2)) = pk;
      }
    }
    __syncthreads();   // B4: H2 complete

    // ---- layer 3: C3[16][32 own samples] + composite ----
    f32x4 acc3[2] = {};
#pragma unroll
    for (int st2 = 0; st2 < 2; ++st2)
#pragma unroll
      for (int kk = 0; kk < 4; ++kk) {
        s16x8 hbf = *(const s16x8*)(Hb + swzH(wv * 32 + st2 * 16 + cl, (kk * 32 + kg * 8) * 2));
        acc3[st2] = __builtin_amdgcn_mfma_f32_16x16x32_bf16(w3f[kk], hbf, acc3[st2], 0, 0, 0);
      }
    if (kg == 0) {   // rgb rows 0..2 live in kg==0 regs 0..2
#pragma unroll
      for (int st2 = 0; st2 < 2; ++st2) {
        float w = wbuf[sBase + wv * 32 + st2 * 16 + cl];
        pw += w;
        pr += w / (1.0f + __expf(-(acc3[st2][0] + b30)));
        pg += w / (1.0f + __expf(-(acc3[st2][1] + b31)));
        pb += w / (1.0f + __expf(-(acc3[st2][2] + b32)));
      }
    }
    // next-chunk stage writes Xf only after B1; L3 reads of H precede next B1 in program order
  }

  // ---------------- final reduce + composite ----------------
  if (kg == 0) {
#pragma unroll
    for (int d = 1; d < 16; d <<= 1) {
      pr += __shfl_xor(pr, d, 64);
      pg += __shfl_xor(pg, d, 64);
      pb += __shfl_xor(pb, d, 64);
      pw += __shfl_xor(pw, d, 64);
    }
    if (lane == 0) { red[wv][0] = pr; red[wv][1] = pg; red[wv][2] = pb; red[wv][3] = pw; }
  }
  __syncthreads();
  if (t == 0) {
    float R = 0, G = 0, B = 0, W = 0;
#pragma unroll
    for (int w = 0; w < 4; ++w) { R += red[w][0]; G += red[w][1]; B += red[w][2]; W += red[w][3]; }
    float bg = 1.0f - W;
    out[r * 3 + 0] = fminf(fmaxf(R + bg, 0.0f), 1.0f);
    out[r * 3 + 1] = fminf(fmaxf(G + bg, 0.0f), 1.0f);
    out[r * 3 + 2] = fminf(fmaxf(B + bg, 0.0f), 1.0f);
  }
}

extern "C" void kernel_launch(void* const* d_in, const int* in_sizes, int n_in,
                              void* d_out, int out_size, void* d_ws, size_t ws_size,
                              hipStream_t stream) {
  const float* dens = (const float*)d_in[0];
  const float* app  = (const float*)d_in[1];
  const float* vd   = (const float*)d_in[2];
  const float* dist = (const float*)d_in[3];
  const float* W1   = (const float*)d_in[4];
  const float* b1   = (const float*)d_in[5];
  const float* W2   = (const float*)d_in[6];
  const float* b2   = (const float*)d_in[7];
  const float* W3   = (const float*)d_in[8];
  const float* b3   = (const float*)d_in[9];
  unsigned short* wsb = (unsigned short*)d_ws;

  prep_weights<<<32, 256, 0, stream>>>(W1, W2, W3, wsb);
  nerf_main<<<4096, 256, 0, stream>>>(dens, app, vd, dist, W1, b1, b2, b3, wsb, (float*)d_out);
}

// Round 5
// 105.936 us; speedup vs baseline: 2.0155x; 2.0155x over previous
//
#include <hip/hip_runtime.h>
#include <hip/hip_bf16.h>

typedef float f32x4 __attribute__((ext_vector_type(4)));
typedef short s16x8 __attribute__((ext_vector_type(8)));
typedef unsigned int u32;
typedef u32 u32x2 __attribute__((ext_vector_type(2)));

#define DIST_SCALE 25.0f

__device__ __forceinline__ unsigned short f2b(float f) {
  union { float f; unsigned u; } v; v.f = f;
  unsigned r = v.u + 0x7fffu + ((v.u >> 16) & 1u);
  return (unsigned short)(r >> 16);
}

__device__ __forceinline__ u32 cvtpk(float lo, float hi) {
  u32 r;
  asm("v_cvt_pk_bf16_f32 %0, %1, %2" : "=v"(r) : "v"(lo), "v"(hi));
  return r;
}

// H: [128 samples][128 ch] bf16, 256B rows, XOR-swizzled
__device__ __forceinline__ int swzH(int s, int chbyte) {
  return (s * 256 + chbyte) ^ ((s & 7) << 4);
}

__global__ void prep_weights(const float* __restrict__ W1, const float* __restrict__ W2,
                             const float* __restrict__ W3, unsigned short* __restrict__ ws) {
  int t = blockIdx.x * 256 + threadIdx.x;
  int stride = gridDim.x * 256;
  // W1aT[n][k] (k padded 27->32 with ZEROS - annihilates X pad garbage)
  for (int i = t; i < 128 * 32; i += stride) {
    int n = i >> 5, k = i & 31;
    ws[i] = (k < 27) ? f2b(W1[k * 128 + n]) : (unsigned short)0;
  }
  unsigned short* w2t = ws + 4096;
  for (int i = t; i < 128 * 128; i += stride) {
    int n = i >> 7, k = i & 127;
    w2t[i] = f2b(W2[k * 128 + n]);
  }
  unsigned short* w3t = ws + 4096 + 16384;   // W3T[n(16 pad)][k(128)]
  for (int i = t; i < 16 * 128; i += stride) {
    int n = i >> 7, k = i & 127;
    w3t[i] = (n < 3) ? f2b(W3[k * 3 + n]) : (unsigned short)0;
  }
}

__global__ __launch_bounds__(256, 3) void nerf_main(
    const float* __restrict__ dens, const float* __restrict__ app,
    const float* __restrict__ vdirs, const float* __restrict__ dists,
    const float* __restrict__ W1, const float* __restrict__ b1,
    const float* __restrict__ b2v, const float* __restrict__ b3v,
    const unsigned short* __restrict__ wsb, float* __restrict__ out) {
  __shared__ float Xf[128 * 27 + 8];          // block-shared f32 staging (+8 zero pad)
  __shared__ unsigned short H[128 * 128];     // block-shared activations [s][ch], in-place L2
  __shared__ float wbuf[256];
  __shared__ float hcbuf[128];
  __shared__ float b2s[128];
  __shared__ float featbuf[40];
  __shared__ float red[4][4];

  const int t = threadIdx.x;
  const int lane = t & 63;
  const int wv = t >> 6;
  const int r = blockIdx.x;

  const unsigned short* W1aT = wsb;
  const unsigned short* W2T = wsb + 4096;
  const unsigned short* W3T = wsb + 4096 + 16384;
  char* Hb = (char*)H;

  const int cl = lane & 15;    // A-row / C-col index
  const int kg = lane >> 4;    // k-group; C rows = kg*4+i
  const int chBase = wv * 32;  // this wave's output-channel slice

  // ---------------- prologue ----------------
  if (t < 39) {   // view-dir features: [vd(3), sin(18), cos(18)]
    float val;
    if (t < 3) val = vdirs[r * 3 + t];
    else {
      int jj = t - 3;
      int trig = jj / 18;
      int rem = jj % 18;
      int c = rem / 6, k = rem % 6;
      float v = vdirs[r * 3 + c] * (float)(1 << k);
      val = trig ? cosf(v) : sinf(v);
    }
    featbuf[t] = val;
  }
  if (t >= 64 && t < 192) b2s[t - 64] = b2v[t - 64];
  if (t < 8) Xf[3456 + t] = 0.0f;   // zero pad: finite for s=127 k>=27 reads
  // transmittance/weight scan (wave 0, 4 samples/lane)
  if (wv == 0) {
    const float4 dv = *(const float4*)(dens + (size_t)r * 256 + lane * 4);
    const float4 tv = *(const float4*)(dists + (size_t)r * 256 + lane * 4);
    float f[4], al[4];
    float dl[4] = {dv.x, dv.y, dv.z, dv.w};
    float tl[4] = {tv.x, tv.y, tv.z, tv.w};
    float p = 1.0f;
#pragma unroll
    for (int q = 0; q < 4; ++q) {
      float sg = fmaxf(dl[q], 0.0f);
      float e = __expf(-sg * tl[q] * DIST_SCALE);
      al[q] = 1.0f - e;
      f[q] = e + 1e-10f;
      p *= f[q];
    }
    float P = p;
#pragma unroll
    for (int dlt = 1; dlt < 64; dlt <<= 1) {
      float v = __shfl_up(P, dlt, 64);
      if (lane >= dlt) P *= v;
    }
    float E = __shfl_up(P, 1, 64);
    if (lane == 0) E = 1.0f;
    float tr = E;
#pragma unroll
    for (int q = 0; q < 4; ++q) { wbuf[lane * 4 + q] = al[q] * tr; tr *= f[q]; }
  }
  __syncthreads();
  // per-ray folded layer-1 bias: h1c = b1 + vd_feats @ W1[27:66]
  if (t < 128) {
    float s = b1[t];
    for (int j = 0; j < 39; ++j) s += featbuf[j] * W1[(27 + j) * 128 + t];
    hcbuf[t] = s;
  }

  // ---- hoist this wave's weight slice into registers (one-time, 56 VGPR) ----
  s16x8 w1f[2], w2f[2][4], w3f[4];
#pragma unroll
  for (int nt = 0; nt < 2; ++nt)
    w1f[nt] = *(const s16x8*)(W1aT + (chBase + nt * 16 + cl) * 32 + kg * 8);
#pragma unroll
  for (int nt = 0; nt < 2; ++nt)
#pragma unroll
    for (int kk = 0; kk < 4; ++kk)
      w2f[nt][kk] = *(const s16x8*)(W2T + (chBase + nt * 16 + cl) * 128 + kk * 32 + kg * 8);
#pragma unroll
  for (int kk = 0; kk < 4; ++kk)
    w3f[kk] = *(const s16x8*)(W3T + cl * 128 + kk * 32 + kg * 8);

  __syncthreads();

  float pr = 0.0f, pg = 0.0f, pb = 0.0f, pw = 0.0f;
  const float b30 = b3v[0], b31 = b3v[1], b32 = b3v[2];
  // st-invariant epilogue constants
  const f32x4 hc0 = *(const f32x4*)(hcbuf + chBase + kg * 4);
  const f32x4 hc1 = *(const f32x4*)(hcbuf + chBase + 16 + kg * 4);
  const f32x4 bb0 = *(const f32x4*)(b2s + chBase + kg * 4);
  const f32x4 bb1 = *(const f32x4*)(b2s + chBase + 16 + kg * 4);

  for (int chunk = 0; chunk < 2; ++chunk) {
    const int sBase = chunk * 128;
    // ---- stage: each wave writes its own 32 samples (f32, contiguous, 16B aligned) ----
    {
      const float* slab = app + ((size_t)r * 256 + sBase + wv * 32) * 27;  // 864 f32
      float* Xw = Xf + wv * 864;
      f32x4 w0 = *(const f32x4*)(slab + 4 * lane);
      f32x4 w1 = *(const f32x4*)(slab + 4 * (lane + 64));
      f32x4 w2 = *(const f32x4*)(slab + 4 * (lane + 128));
      *(f32x4*)(Xw + 4 * lane) = w0;
      *(f32x4*)(Xw + 4 * (lane + 64)) = w1;
      *(f32x4*)(Xw + 4 * (lane + 128)) = w2;
      if (lane < 24) {
        f32x4 w3 = *(const f32x4*)(slab + 4 * (lane + 192));
        *(f32x4*)(Xw + 4 * (lane + 192)) = w3;
      }
    }
    __syncthreads();   // B1: X staged

    // ---- layer 1 (streamed per sample-tile, acc liveness = 8 regs) ----
#pragma unroll
    for (int st = 0; st < 8; ++st) {
      const float* xr = Xf + 27 * (st * 16 + cl) + 8 * kg;  // k>=27 garbage killed by zero W cols
      union { u32 u[4]; s16x8 v; } ub;
#pragma unroll
      for (int p2 = 0; p2 < 4; ++p2) ub.u[p2] = cvtpk(xr[2 * p2], xr[2 * p2 + 1]);
      f32x4 a0 = {}, a1 = {};
      a0 = __builtin_amdgcn_mfma_f32_16x16x32_bf16(w1f[0], ub.v, a0, 0, 0, 0);
      a1 = __builtin_amdgcn_mfma_f32_16x16x32_bf16(w1f[1], ub.v, a1, 0, 0, 0);
      const int s = st * 16 + cl;
      u32x2 pk0 = {cvtpk(fmaxf(a0[0] + hc0[0], 0.0f), fmaxf(a0[1] + hc0[1], 0.0f)),
                   cvtpk(fmaxf(a0[2] + hc0[2], 0.0f), fmaxf(a0[3] + hc0[3], 0.0f))};
      u32x2 pk1 = {cvtpk(fmaxf(a1[0] + hc1[0], 0.0f), fmaxf(a1[1] + hc1[1], 0.0f)),
                   cvtpk(fmaxf(a1[2] + hc1[2], 0.0f), fmaxf(a1[3] + hc1[3], 0.0f))};
      *(u32x2*)(Hb + swzH(s, (chBase + kg * 4) * 2)) = pk0;
      *(u32x2*)(Hb + swzH(s, (chBase + 16 + kg * 4) * 2)) = pk1;
    }
    __syncthreads();   // B2: H1 complete

    // ---- layer 2 in two sample-halves (acc liveness = 32 regs, in-place H) ----
#pragma unroll
    for (int h = 0; h < 2; ++h) {
      f32x4 acc2[2][4] = {};
#pragma unroll
      for (int q = 0; q < 4; ++q) {
        const int st = h * 4 + q;
        s16x8 hbf[4];
#pragma unroll
        for (int kk = 0; kk < 4; ++kk)
          hbf[kk] = *(const s16x8*)(Hb + swzH(st * 16 + cl, (kk * 32 + kg * 8) * 2));
#pragma unroll
        for (int kk = 0; kk < 4; ++kk)
#pragma unroll
          for (int nt = 0; nt < 2; ++nt)
            acc2[nt][q] =
                __builtin_amdgcn_mfma_f32_16x16x32_bf16(w2f[nt][kk], hbf[kk], acc2[nt][q], 0, 0, 0);
      }
      __syncthreads();   // B3a/B3b: all reads of this half done block-wide
#pragma unroll
      for (int q = 0; q < 4; ++q) {
        const int s = (h * 4 + q) * 16 + cl;
        u32x2 pk0 = {cvtpk(fmaxf(acc2[0][q][0] + bb0[0], 0.0f), fmaxf(acc2[0][q][1] + bb0[1], 0.0f)),
                     cvtpk(fmaxf(acc2[0][q][2] + bb0[2], 0.0f), fmaxf(acc2[0][q][3] + bb0[3], 0.0f))};
        u32x2 pk1 = {cvtpk(fmaxf(acc2[1][q][0] + bb1[0], 0.0f), fmaxf(acc2[1][q][1] + bb1[1], 0.0f)),
                     cvtpk(fmaxf(acc2[1][q][2] + bb1[2], 0.0f), fmaxf(acc2[1][q][3] + bb1[3], 0.0f))};
        *(u32x2*)(Hb + swzH(s, (chBase + kg * 4) * 2)) = pk0;
        *(u32x2*)(Hb + swzH(s, (chBase + 16 + kg * 4) * 2)) = pk1;
      }
    }
    __syncthreads();   // B4: H2 complete

    // ---- layer 3: C3[16][32 own samples] + composite ----
    f32x4 acc3[2] = {};
#pragma unroll
    for (int st2 = 0; st2 < 2; ++st2)
#pragma unroll
      for (int kk = 0; kk < 4; ++kk) {
        s16x8 hbf = *(const s16x8*)(Hb + swzH(wv * 32 + st2 * 16 + cl, (kk * 32 + kg * 8) * 2));
        acc3[st2] = __builtin_amdgcn_mfma_f32_16x16x32_bf16(w3f[kk], hbf, acc3[st2], 0, 0, 0);
      }
    if (kg == 0) {   // rgb rows 0..2 live in kg==0 regs 0..2
#pragma unroll
      for (int st2 = 0; st2 < 2; ++st2) {
        float w = wbuf[sBase + wv * 32 + st2 * 16 + cl];
        pw += w;
        pr += w / (1.0f + __expf(-(acc3[st2][0] + b30)));
        pg += w / (1.0f + __expf(-(acc3[st2][1] + b31)));
        pb += w / (1.0f + __expf(-(acc3[st2][2] + b32)));
      }
    }
    // next-chunk stage of Xf / L1 H-writes are fenced by the next B1
  }

  // ---------------- final reduce + composite ----------------
  if (kg == 0) {
#pragma unroll
    for (int d = 1; d < 16; d <<= 1) {
      pr += __shfl_xor(pr, d, 64);
      pg += __shfl_xor(pg, d, 64);
      pb += __shfl_xor(pb, d, 64);
      pw += __shfl_xor(pw, d, 64);
    }
    if (lane == 0) { red[wv][0] = pr; red[wv][1] = pg; red[wv][2] = pb; red[wv][3] = pw; }
  }
  __syncthreads();
  if (t == 0) {
    float R = 0, G = 0, B = 0, W = 0;
#pragma unroll
    for (int w = 0; w < 4; ++w) { R += red[w][0]; G += red[w][1]; B += red[w][2]; W += red[w][3]; }
    float bg = 1.0f - W;
    out[r * 3 + 0] = fminf(fmaxf(R + bg, 0.0f), 1.0f);
    out[r * 3 + 1] = fminf(fmaxf(G + bg, 0.0f), 1.0f);
    out[r * 3 + 2] = fminf(fmaxf(B + bg, 0.0f), 1.0f);
  }
}

extern "C" void kernel_launch(void* const* d_in, const int* in_sizes, int n_in,
                              void* d_out, int out_size, void* d_ws, size_t ws_size,
                              hipStream_t stream) {
  const float* dens = (const float*)d_in[0];
  const float* app  = (const float*)d_in[1];
  const float* vd   = (const float*)d_in[2];
  const float* dist = (const float*)d_in[3];
  const float* W1   = (const float*)d_in[4];
  const float* b1   = (const float*)d_in[5];
  const float* W2   = (const float*)d_in[6];
  const float* b2   = (const float*)d_in[7];
  const float* W3   = (const float*)d_in[8];
  const float* b3   = (const float*)d_in[9];
  unsigned short* wsb = (unsigned short*)d_ws;

  prep_weights<<<32, 256, 0, stream>>>(W1, W2, W3, wsb);
  nerf_main<<<4096, 256, 0, stream>>>(dens, app, vd, dist, W1, b1, b2, b3, wsb, (float*)d_out);
}

// Round 6
// 100.775 us; speedup vs baseline: 2.1188x; 1.0512x over previous
//
#include <hip/hip_runtime.h>
#include <hip/hip_bf16.h>

typedef float f32x4 __attribute__((ext_vector_type(4)));
typedef short s16x8 __attribute__((ext_vector_type(8)));
typedef unsigned int u32;
typedef u32 u32x2 __attribute__((ext_vector_type(2)));

#define DIST_SCALE 25.0f

__device__ __forceinline__ unsigned short f2b(float f) {
  union { float f; unsigned u; } v; v.f = f;
  unsigned r = v.u + 0x7fffu + ((v.u >> 16) & 1u);
  return (unsigned short)(r >> 16);
}

__device__ __forceinline__ u32 cvtpk(float lo, float hi) {
  u32 r;
  asm("v_cvt_pk_bf16_f32 %0, %1, %2" : "=v"(r) : "v"(lo), "v"(hi));
  return r;
}

// H: [64 samples][128 ch] bf16, 256B rows, XOR-swizzled
__device__ __forceinline__ int swzH(int s, int chbyte) {
  return (s * 256 + chbyte) ^ ((s & 7) << 4);
}

__global__ void prep_weights(const float* __restrict__ W1, const float* __restrict__ W2,
                             const float* __restrict__ W3, unsigned short* __restrict__ ws) {
  int t = blockIdx.x * 256 + threadIdx.x;
  int stride = gridDim.x * 256;
  // W1aT[n][k] (k padded 27->32 with ZEROS - annihilates X pad garbage)
  for (int i = t; i < 128 * 32; i += stride) {
    int n = i >> 5, k = i & 31;
    ws[i] = (k < 27) ? f2b(W1[k * 128 + n]) : (unsigned short)0;
  }
  unsigned short* w2t = ws + 4096;
  for (int i = t; i < 128 * 128; i += stride) {
    int n = i >> 7, k = i & 127;
    w2t[i] = f2b(W2[k * 128 + n]);
  }
  unsigned short* w3t = ws + 4096 + 16384;   // W3T[n(16 pad)][k(128)]
  for (int i = t; i < 16 * 128; i += stride) {
    int n = i >> 7, k = i & 127;
    w3t[i] = (n < 3) ? f2b(W3[k * 3 + n]) : (unsigned short)0;
  }
}

__global__ __launch_bounds__(256, 4) void nerf_main(
    const float* __restrict__ dens, const float* __restrict__ app,
    const float* __restrict__ vdirs, const float* __restrict__ dists,
    const float* __restrict__ W1, const float* __restrict__ b1,
    const float* __restrict__ b2v, const float* __restrict__ b3v,
    const unsigned short* __restrict__ wsb, float* __restrict__ out) {
  __shared__ float Xf[64 * 27 + 8];           // 6.9 KB f32 staging (+8 zero pad)
  __shared__ unsigned short H[64 * 128];      // 16 KB activations [s][ch], in-place L2
  __shared__ float wbuf[256];
  __shared__ float hcbuf[128];
  __shared__ float b2s[128];
  __shared__ float featbuf[40];
  __shared__ float red[4][4];

  const int t = threadIdx.x;
  const int lane = t & 63;
  const int wv = t >> 6;
  const int r = blockIdx.x;

  const unsigned short* W1aT = wsb;
  const unsigned short* W2T = wsb + 4096;
  const unsigned short* W3T = wsb + 4096 + 16384;
  char* Hb = (char*)H;

  const int cl = lane & 15;    // A-row / C-col index
  const int kg = lane >> 4;    // k-group; C rows = kg*4+i
  const int chBase = wv * 32;  // this wave's output-channel slice

  // ---------------- prologue ----------------
  if (t < 39) {   // view-dir features: [vd(3), sin(18), cos(18)]
    float val;
    if (t < 3) val = vdirs[r * 3 + t];
    else {
      int jj = t - 3;
      int trig = jj / 18;
      int rem = jj % 18;
      int c = rem / 6, k = rem % 6;
      float v = vdirs[r * 3 + c] * (float)(1 << k);
      val = trig ? cosf(v) : sinf(v);
    }
    featbuf[t] = val;
  }
  if (t >= 64 && t < 192) b2s[t - 64] = b2v[t - 64];
  if (t < 8) Xf[1728 + t] = 0.0f;   // zero pad: finite for s=63 k>=27 reads
  // transmittance/weight scan (wave 0, 4 samples/lane)
  if (wv == 0) {
    const float4 dv = *(const float4*)(dens + (size_t)r * 256 + lane * 4);
    const float4 tv = *(const float4*)(dists + (size_t)r * 256 + lane * 4);
    float f[4], al[4];
    float dl[4] = {dv.x, dv.y, dv.z, dv.w};
    float tl[4] = {tv.x, tv.y, tv.z, tv.w};
    float p = 1.0f;
#pragma unroll
    for (int q = 0; q < 4; ++q) {
      float sg = fmaxf(dl[q], 0.0f);
      float e = __expf(-sg * tl[q] * DIST_SCALE);
      al[q] = 1.0f - e;
      f[q] = e + 1e-10f;
      p *= f[q];
    }
    float P = p;
#pragma unroll
    for (int dlt = 1; dlt < 64; dlt <<= 1) {
      float v = __shfl_up(P, dlt, 64);
      if (lane >= dlt) P *= v;
    }
    float E = __shfl_up(P, 1, 64);
    if (lane == 0) E = 1.0f;
    float tr = E;
#pragma unroll
    for (int q = 0; q < 4; ++q) { wbuf[lane * 4 + q] = al[q] * tr; tr *= f[q]; }
  }
  __syncthreads();
  // per-ray folded layer-1 bias: h1c = b1 + vd_feats @ W1[27:66]
  if (t < 128) {
    float s = b1[t];
    for (int j = 0; j < 39; ++j) s += featbuf[j] * W1[(27 + j) * 128 + t];
    hcbuf[t] = s;
  }

  // ---- hoist this wave's weight slice into registers (one-time, 56 VGPR) ----
  s16x8 w1f[2], w2f[2][4], w3f[4];
#pragma unroll
  for (int nt = 0; nt < 2; ++nt)
    w1f[nt] = *(const s16x8*)(W1aT + (chBase + nt * 16 + cl) * 32 + kg * 8);
#pragma unroll
  for (int nt = 0; nt < 2; ++nt)
#pragma unroll
    for (int kk = 0; kk < 4; ++kk)
      w2f[nt][kk] = *(const s16x8*)(W2T + (chBase + nt * 16 + cl) * 128 + kk * 32 + kg * 8);
#pragma unroll
  for (int kk = 0; kk < 4; ++kk)
    w3f[kk] = *(const s16x8*)(W3T + cl * 128 + kk * 32 + kg * 8);

  __syncthreads();

  float pr = 0.0f, pg = 0.0f, pb = 0.0f, pw = 0.0f;
  const float b30 = b3v[0], b31 = b3v[1], b32 = b3v[2];
  // st-invariant epilogue constants
  const f32x4 hc0 = *(const f32x4*)(hcbuf + chBase + kg * 4);
  const f32x4 hc1 = *(const f32x4*)(hcbuf + chBase + 16 + kg * 4);
  const f32x4 bb0 = *(const f32x4*)(b2s + chBase + kg * 4);
  const f32x4 bb1 = *(const f32x4*)(b2s + chBase + 16 + kg * 4);

  // ---- preload chunk 0 staging into registers (block-linear, coalesced) ----
  const float* rayBase = app + (size_t)r * 256 * 27;
  f32x4 L0 = *(const f32x4*)(rayBase + 4 * t);
  f32x4 L1 = {};
  if (t < 176) L1 = *(const f32x4*)(rayBase + 4 * (t + 256));

  for (int chunk = 0; chunk < 4; ++chunk) {
    const int sBase = chunk * 64;
    // ---- commit prefetched X (1728 f32 = 432 f32x4, block-linear) ----
    *(f32x4*)(Xf + 4 * t) = L0;
    if (t < 176) *(f32x4*)(Xf + 4 * (t + 256)) = L1;
    __syncthreads();   // B1: Xf ready; also fences prev-chunk L3 H-reads vs new H1 writes

    // ---- prefetch next chunk into regs (latency hides under L1+L2 compute) ----
    if (chunk < 3) {
      const float* slab = rayBase + (size_t)(chunk + 1) * 64 * 27;
      L0 = *(const f32x4*)(slab + 4 * t);
      if (t < 176) L1 = *(const f32x4*)(slab + 4 * (t + 256));
    }

    // ---- layer 1 (streamed per sample-tile, acc liveness = 8 regs) ----
#pragma unroll
    for (int st = 0; st < 4; ++st) {
      const float* xr = Xf + 27 * (st * 16 + cl) + 8 * kg;  // k>=27 garbage killed by zero W cols
      union { u32 u[4]; s16x8 v; } ub;
#pragma unroll
      for (int p2 = 0; p2 < 4; ++p2) ub.u[p2] = cvtpk(xr[2 * p2], xr[2 * p2 + 1]);
      f32x4 a0 = {}, a1 = {};
      a0 = __builtin_amdgcn_mfma_f32_16x16x32_bf16(w1f[0], ub.v, a0, 0, 0, 0);
      a1 = __builtin_amdgcn_mfma_f32_16x16x32_bf16(w1f[1], ub.v, a1, 0, 0, 0);
      const int s = st * 16 + cl;
      u32x2 pk0 = {cvtpk(fmaxf(a0[0] + hc0[0], 0.0f), fmaxf(a0[1] + hc0[1], 0.0f)),
                   cvtpk(fmaxf(a0[2] + hc0[2], 0.0f), fmaxf(a0[3] + hc0[3], 0.0f))};
      u32x2 pk1 = {cvtpk(fmaxf(a1[0] + hc1[0], 0.0f), fmaxf(a1[1] + hc1[1], 0.0f)),
                   cvtpk(fmaxf(a1[2] + hc1[2], 0.0f), fmaxf(a1[3] + hc1[3], 0.0f))};
      *(u32x2*)(Hb + swzH(s, (chBase + kg * 4) * 2)) = pk0;
      *(u32x2*)(Hb + swzH(s, (chBase + 16 + kg * 4) * 2)) = pk1;
    }
    __syncthreads();   // B2: H1 complete

    // ---- layer 2 in two sample-halves (acc liveness = 16 regs, in-place H) ----
#pragma unroll
    for (int h = 0; h < 2; ++h) {
      f32x4 acc2[2][2] = {};
#pragma unroll
      for (int q = 0; q < 2; ++q) {
        const int st = h * 2 + q;
        s16x8 hbf[4];
#pragma unroll
        for (int kk = 0; kk < 4; ++kk)
          hbf[kk] = *(const s16x8*)(Hb + swzH(st * 16 + cl, (kk * 32 + kg * 8) * 2));
#pragma unroll
        for (int kk = 0; kk < 4; ++kk)
#pragma unroll
          for (int nt = 0; nt < 2; ++nt)
            acc2[nt][q] =
                __builtin_amdgcn_mfma_f32_16x16x32_bf16(w2f[nt][kk], hbf[kk], acc2[nt][q], 0, 0, 0);
      }
      __syncthreads();   // all reads of this half done block-wide
#pragma unroll
      for (int q = 0; q < 2; ++q) {
        const int s = (h * 2 + q) * 16 + cl;
        u32x2 pk0 = {cvtpk(fmaxf(acc2[0][q][0] + bb0[0], 0.0f), fmaxf(acc2[0][q][1] + bb0[1], 0.0f)),
                     cvtpk(fmaxf(acc2[0][q][2] + bb0[2], 0.0f), fmaxf(acc2[0][q][3] + bb0[3], 0.0f))};
        u32x2 pk1 = {cvtpk(fmaxf(acc2[1][q][0] + bb1[0], 0.0f), fmaxf(acc2[1][q][1] + bb1[1], 0.0f)),
                     cvtpk(fmaxf(acc2[1][q][2] + bb1[2], 0.0f), fmaxf(acc2[1][q][3] + bb1[3], 0.0f))};
        *(u32x2*)(Hb + swzH(s, (chBase + kg * 4) * 2)) = pk0;
        *(u32x2*)(Hb + swzH(s, (chBase + 16 + kg * 4) * 2)) = pk1;
      }
    }
    __syncthreads();   // B4: H2 complete

    // ---- layer 3: C3[16][16 own samples] + composite ----
    f32x4 acc3 = {};
#pragma unroll
    for (int kk = 0; kk < 4; ++kk) {
      s16x8 hbf = *(const s16x8*)(Hb + swzH(wv * 16 + cl, (kk * 32 + kg * 8) * 2));
      acc3 = __builtin_amdgcn_mfma_f32_16x16x32_bf16(w3f[kk], hbf, acc3, 0, 0, 0);
    }
    if (kg == 0) {   // rgb rows 0..2 live in kg==0 regs 0..2
      float w = wbuf[sBase + wv * 16 + cl];
      pw += w;
      pr += w / (1.0f + __expf(-(acc3[0] + b30)));
      pg += w / (1.0f + __expf(-(acc3[1] + b31)));
      pb += w / (1.0f + __expf(-(acc3[2] + b32)));
    }
    // loop back: Xf rewrite is fenced by B2+B4 (all waves past their L1 X-reads);
    // new H1 writes are fenced by next B1 (all waves past their L3 H-reads)
  }

  // ---------------- final reduce + composite ----------------
  if (kg == 0) {
#pragma unroll
    for (int d = 1; d < 16; d <<= 1) {
      pr += __shfl_xor(pr, d, 64);
      pg += __shfl_xor(pg, d, 64);
      pb += __shfl_xor(pb, d, 64);
      pw += __shfl_xor(pw, d, 64);
    }
    if (lane == 0) { red[wv][0] = pr; red[wv][1] = pg; red[wv][2] = pb; red[wv][3] = pw; }
  }
  __syncthreads();
  if (t == 0) {
    float R = 0, G = 0, B = 0, W = 0;
#pragma unroll
    for (int w = 0; w < 4; ++w) { R += red[w][0]; G += red[w][1]; B += red[w][2]; W += red[w][3]; }
    float bg = 1.0f - W;
    out[r * 3 + 0] = fminf(fmaxf(R + bg, 0.0f), 1.0f);
    out[r * 3 + 1] = fminf(fmaxf(G + bg, 0.0f), 1.0f);
    out[r * 3 + 2] = fminf(fmaxf(B + bg, 0.0f), 1.0f);
  }
}

extern "C" void kernel_launch(void* const* d_in, const int* in_sizes, int n_in,
                              void* d_out, int out_size, void* d_ws, size_t ws_size,
                              hipStream_t stream) {
  const float* dens = (const float*)d_in[0];
  const float* app  = (const float*)d_in[1];
  const float* vd   = (const float*)d_in[2];
  const float* dist = (const float*)d_in[3];
  const float* W1   = (const float*)d_in[4];
  const float* b1   = (const float*)d_in[5];
  const float* W2   = (const float*)d_in[6];
  const float* b2   = (const float*)d_in[7];
  const float* W3   = (const float*)d_in[8];
  const float* b3   = (const float*)d_in[9];
  unsigned short* wsb = (unsigned short*)d_ws;

  prep_weights<<<32, 256, 0, stream>>>(W1, W2, W3, wsb);
  nerf_main<<<4096, 256, 0, stream>>>(dens, app, vd, dist, W1, b1, b2, b3, wsb, (float*)d_out);
}